// Round 6
// baseline (323.950 us; speedup 1.0000x reference)
//
#include <hip/hip_runtime.h>

// HausdorffLoss (average): B=8, N=M=4096, C=128, fp32 in/out.
// R6: A-fragments loaded directly from the pre-swizzled global bf16 image
// (no A LDS); LDS = B double-buffer only (32 KB -> 4 blocks/CU); colmin
// atomics deferred past the K-loop so the per-iter barrier drains only the
// B prefetch. MFMA 16x16x32 bf16, min-of-d2, sqrt deferred.
#define B_ 8
#define N_ 4096
#define M_ 4096
#define C_ 128
#define BN_ (B_ * N_)
#define BM_ (B_ * M_)

typedef __attribute__((ext_vector_type(8))) short bf16x8;    // MFMA A/B frag
typedef __attribute__((ext_vector_type(4))) float floatx4;   // MFMA C/D frag
typedef __attribute__((ext_vector_type(8))) unsigned short ushort8;

// fp32 -> bf16 round-to-nearest-even
__device__ __forceinline__ unsigned short f2bf(float x) {
    unsigned int u = __float_as_uint(x);
    u += 0x7FFFu + ((u >> 16) & 1u);
    return (unsigned short)(u >> 16);
}

// async global->LDS, 16 B per lane; LDS dest = wave-uniform base + lane*16
__device__ __forceinline__ void gl2lds16(const void* g, void* l) {
    __builtin_amdgcn_global_load_lds(
        (const __attribute__((address_space(1))) void*)g,
        (__attribute__((address_space(3))) void*)l, 16, 0, 0);
}

// ---------------------------------------------------------------------------
// Prep: bf16 convert (swizzled: ws[row][g ^ (row&15)] = src[row][g]),
// norms[row] = ||row||^2 (fp32), minbuf[row] = +inf, out zero-init.
// Wave handles 4 rows: lane = (row_in_4 : 2, k-group : 4).
// Grid = (BN_+BM_)/16 = 4096 blocks x 256 threads.
// ---------------------------------------------------------------------------
__global__ __launch_bounds__(256) void prep_kernel(
    const float* __restrict__ S1, const float* __restrict__ S2,
    unsigned int* __restrict__ minbuf, float* __restrict__ norms,
    unsigned short* __restrict__ bfA, unsigned short* __restrict__ bfB,
    float* __restrict__ out) {
    const int lane = threadIdx.x & 63;
    const int w    = threadIdx.x >> 6;
    const int gw   = blockIdx.x * 4 + w;
    const int r4   = lane >> 4;
    const int g4   = lane & 15;
    const int row  = gw * 4 + r4;          // 0 .. BN_+BM_-1

    const float* src = (row < BN_) ? S1 + (size_t)row * C_
                                   : S2 + (size_t)(row - BN_) * C_;
    float4 v0 = ((const float4*)src)[g4 * 2];
    float4 v1 = ((const float4*)src)[g4 * 2 + 1];

    float s = v0.x*v0.x + v0.y*v0.y + v0.z*v0.z + v0.w*v0.w
            + v1.x*v1.x + v1.y*v1.y + v1.z*v1.z + v1.w*v1.w;
    s += __shfl_xor(s, 1, 64);
    s += __shfl_xor(s, 2, 64);
    s += __shfl_xor(s, 4, 64);
    s += __shfl_xor(s, 8, 64);

    ushort8 o;
    o[0] = f2bf(v0.x); o[1] = f2bf(v0.y); o[2] = f2bf(v0.z); o[3] = f2bf(v0.w);
    o[4] = f2bf(v1.x); o[5] = f2bf(v1.y); o[6] = f2bf(v1.z); o[7] = f2bf(v1.w);

    unsigned short* dst = (row < BN_) ? bfA + (size_t)row * C_
                                      : bfB + (size_t)(row - BN_) * C_;
    *(ushort8*)&dst[(g4 ^ (row & 15)) * 8] = o;

    if (g4 == 0) { norms[row] = s; minbuf[row] = 0x7F800000u; }
    if (blockIdx.x == 0 && threadIdx.x < B_) out[threadIdx.x] = 0.f;
}

// ---------------------------------------------------------------------------
// Main: grid (N/128, M/1024, B). 4 waves; wave tile = 64 rows x 32 cols.
// LDS: B double-buffered 64-col tiles only (2 x 16 KB = 32 KB).
// ---------------------------------------------------------------------------
__global__ __launch_bounds__(256, 4) void hausdorff_mfma(
    const unsigned short* __restrict__ Abf, const unsigned short* __restrict__ Bbf,
    const float* __restrict__ asq_g, const float* __restrict__ bsq_g,
    unsigned int* __restrict__ rowmin, unsigned int* __restrict__ colmin) {

    __shared__ unsigned short B_lds[2][64 * 128];   // 2 x 16 KB

    const int b     = blockIdx.z;
    const int row0  = blockIdx.x * 128;
    const int panel = blockIdx.y;                   // cols panel*1024 ..
    const int tid   = threadIdx.x;
    const int lane  = tid & 63;
    const int w     = tid >> 6;
    const int lm    = lane & 15;
    const int quad  = lane >> 4;
    const int wrow  = (w >> 1) * 64;                // wave's row half
    const int qc    = (w & 1) * 32;                 // wave's col half (of 64)

    const unsigned short* Aws = Abf + ((size_t)b * N_ + row0) * C_;
    const unsigned short* Bws = Bbf + ((size_t)b * M_ + panel * 1024) * C_;

    // stage B tile 0
    #pragma unroll
    for (int k = 0; k < 4; ++k) {
        const int off = w * 2048 + k * 512;
        gl2lds16(Bws + off + lane * 8, &B_lds[0][off]);
    }

    // A fragments straight from the pre-swizzled global image (row&15 == lm
    // for every fragment row, so the XOR key matches the stored layout).
    bf16x8 af[4][4];
    #pragma unroll
    for (int i = 0; i < 4; ++i)
        #pragma unroll
        for (int c = 0; c < 4; ++c)
            af[i][c] = *(const bf16x8*)
                &Aws[(wrow + 16 * i + lm) * 128 + (((c * 4 + quad) ^ lm) * 8)];

    // row norms for this lane's 16 rows: wrow + 16i + 4*quad + reg
    float sa[16];
    #pragma unroll
    for (int i = 0; i < 4; ++i) {
        float4 t = *(const float4*)&asq_g[(size_t)b * N_ + row0 + wrow + 16 * i + 4 * quad];
        sa[4*i+0] = t.x; sa[4*i+1] = t.y; sa[4*i+2] = t.z; sa[4*i+3] = t.w;
    }

    float rv[16];
    #pragma unroll
    for (int v = 0; v < 16; ++v) rv[v] = 1e30f;
    float cvb0[16], cvb1[16];              // per-iter col mins (flushed at end)

    __syncthreads();   // B0 staged

    for (int it = 0; it < 16; ++it) {
        const int cur = it & 1;
        if (it < 15) {   // stage next tile into the other buffer
            const unsigned short* Bt = Bws + (size_t)(it + 1) * 64 * C_;
            #pragma unroll
            for (int k = 0; k < 4; ++k) {
                const int off = w * 2048 + k * 512;
                gl2lds16(Bt + off + lane * 8, &B_lds[cur ^ 1][off]);
            }
        }
        const int colbase = panel * 1024 + it * 64;
        const float sb0 = bsq_g[(size_t)b * M_ + colbase + qc + lm];
        const float sb1 = bsq_g[(size_t)b * M_ + colbase + qc + 16 + lm];

        bf16x8 bf[2][4];
        #pragma unroll
        for (int j = 0; j < 2; ++j)
            #pragma unroll
            for (int c = 0; c < 4; ++c)
                bf[j][c] = *(const bf16x8*)
                    &B_lds[cur][(qc + 16 * j + lm) * 128 + (((c * 4 + quad) ^ lm) * 8)];

        floatx4 acc[4][2] = {};
        #pragma unroll
        for (int c = 0; c < 4; ++c)
            #pragma unroll
            for (int i = 0; i < 4; ++i)
                #pragma unroll
                for (int j = 0; j < 2; ++j)
                    acc[i][j] = __builtin_amdgcn_mfma_f32_16x16x32_bf16(
                        af[i][c], bf[j][c], acc[i][j], 0, 0, 0);

        float cv0 = 1e30f, cv1 = 1e30f;
        #pragma unroll
        for (int i = 0; i < 4; ++i)
            #pragma unroll
            for (int reg = 0; reg < 4; ++reg) {
                const int v = 4 * i + reg;
                float d0 = fmaf(-2.0f, acc[i][0][reg], sa[v] + sb0);
                float d1 = fmaf(-2.0f, acc[i][1][reg], sa[v] + sb1);
                rv[v] = fminf(rv[v], fminf(d0, d1));   // -> v_min3
                cv0 = fminf(cv0, d0);
                cv1 = fminf(cv1, d1);
            }
        cvb0[it] = cv0;
        cvb1[it] = cv1;
        __syncthreads();   // buffer swap; drains only the B prefetch
    }

    // ---- deferred col-min reduction + atomics (outside the barrier loop) ----
    #pragma unroll
    for (int it = 0; it < 16; ++it) {
        float cv0 = cvb0[it], cv1 = cvb1[it];
        cv0 = fminf(cv0, __shfl_xor(cv0, 16, 64));
        cv0 = fminf(cv0, __shfl_xor(cv0, 32, 64));
        cv1 = fminf(cv1, __shfl_xor(cv1, 16, 64));
        cv1 = fminf(cv1, __shfl_xor(cv1, 32, 64));
        if (quad == 0) {
            const int colbase = panel * 1024 + it * 64;
            atomicMin(&colmin[(size_t)b * M_ + colbase + qc + lm],
                      __float_as_uint(fmaxf(cv0, 0.f)));
            atomicMin(&colmin[(size_t)b * M_ + colbase + qc + 16 + lm],
                      __float_as_uint(fmaxf(cv1, 0.f)));
        }
    }

    // row mins: butterfly across the 16 lane-cols
    #pragma unroll
    for (int s = 1; s < 16; s <<= 1)
        #pragma unroll
        for (int v = 0; v < 16; ++v)
            rv[v] = fminf(rv[v], __shfl_xor(rv[v], s, 64));
    if (lm == 0) {
        #pragma unroll
        for (int v = 0; v < 16; ++v)
            atomicMin(&rowmin[(size_t)b * N_ + row0 + wrow + 16 * (v >> 2) +
                              4 * quad + (v & 3)],
                      __float_as_uint(fmaxf(rv[v], 0.f)));
    }
}

// ---------------------------------------------------------------------------
// Reduce: 64 blocks (8 per batch), partial sums -> atomicAdd(out[b]).
// ---------------------------------------------------------------------------
__global__ __launch_bounds__(256) void hausdorff_reduce(
    const unsigned int* __restrict__ rowmin,
    const unsigned int* __restrict__ colmin, float* __restrict__ out) {
    __shared__ float ws4[4];
    const int b    = blockIdx.x >> 3;
    const int part = blockIdx.x & 7;
    const int base = part * 512;
    float s = 0.f;
    for (int i = base + threadIdx.x; i < base + 512; i += 256)
        s += sqrtf(fmaxf(__uint_as_float(rowmin[(size_t)b * N_ + i]), 0.f)) * (1.f / N_)
           + sqrtf(fmaxf(__uint_as_float(colmin[(size_t)b * M_ + i]), 0.f)) * (1.f / M_);
    #pragma unroll
    for (int off = 32; off > 0; off >>= 1) s += __shfl_down(s, off, 64);
    if ((threadIdx.x & 63) == 0) ws4[threadIdx.x >> 6] = s;
    __syncthreads();
    if (threadIdx.x == 0)
        atomicAdd(&out[b], ws4[0] + ws4[1] + ws4[2] + ws4[3]);
}

extern "C" void kernel_launch(void* const* d_in, const int* in_sizes, int n_in,
                              void* d_out, int out_size, void* d_ws, size_t ws_size,
                              hipStream_t stream) {
    const float* s1 = (const float*)d_in[0];
    const float* s2 = (const float*)d_in[1];
    float* out = (float*)d_out;

    // ws: rowmin(BN u32) | colmin(BM u32) | norms(BN+BM f32) | bfA | bfB
    unsigned int* rowmin = (unsigned int*)d_ws;
    unsigned int* colmin = rowmin + BN_;
    float* norms         = (float*)(colmin + BM_);
    unsigned short* bfA  = (unsigned short*)(norms + BN_ + BM_);
    unsigned short* bfB  = bfA + (size_t)BN_ * C_;

    prep_kernel<<<(BN_ + BM_) / 16, 256, 0, stream>>>(
        s1, s2, rowmin, norms, bfA, bfB, out);

    dim3 grid(N_ / 128, M_ / 1024, B_);
    hausdorff_mfma<<<grid, 256, 0, stream>>>(
        bfA, bfB, norms, norms + BN_, rowmin, colmin);

    hausdorff_reduce<<<B_ * 8, 256, 0, stream>>>(rowmin, colmin, out);
}

// Round 7
// 198.139 us; speedup vs baseline: 1.6350x; 1.6350x over previous
//
#include <hip/hip_runtime.h>

// HausdorffLoss (average): B=8, N=M=4096, C=128, fp32 in/out.
// R7 = R5 body (96 VGPR, no spills, in-loop atomics) with LDS halved to
// 32 KB: A is staged through the two B double-buffers before the K-loop
// (rows 0-63 -> buf0, 64-127 -> buf1), af-fragments read once to registers,
// then the buffers are recycled for the B pipeline. 4 blocks/CU resident.
#define B_ 8
#define N_ 4096
#define M_ 4096
#define C_ 128
#define BN_ (B_ * N_)
#define BM_ (B_ * M_)

typedef __attribute__((ext_vector_type(8))) short bf16x8;    // MFMA A/B frag
typedef __attribute__((ext_vector_type(4))) float floatx4;   // MFMA C/D frag
typedef __attribute__((ext_vector_type(8))) unsigned short ushort8;

// fp32 -> bf16 round-to-nearest-even
__device__ __forceinline__ unsigned short f2bf(float x) {
    unsigned int u = __float_as_uint(x);
    u += 0x7FFFu + ((u >> 16) & 1u);
    return (unsigned short)(u >> 16);
}

// async global->LDS, 16 B per lane; LDS dest = wave-uniform base + lane*16
__device__ __forceinline__ void gl2lds16(const void* g, void* l) {
    __builtin_amdgcn_global_load_lds(
        (const __attribute__((address_space(1))) void*)g,
        (__attribute__((address_space(3))) void*)l, 16, 0, 0);
}

// ---------------------------------------------------------------------------
// Prep: bf16 convert (swizzled: ws[row][g ^ (row&15)] = src[row][g]),
// norms[row] = ||row||^2 (fp32), minbuf[row] = +inf, out zero-init.
// Wave handles 4 rows: lane = (row_in_4 : 2, k-group : 4).
// Grid = (BN_+BM_)/16 = 4096 blocks x 256 threads.
// ---------------------------------------------------------------------------
__global__ __launch_bounds__(256) void prep_kernel(
    const float* __restrict__ S1, const float* __restrict__ S2,
    unsigned int* __restrict__ minbuf, float* __restrict__ norms,
    unsigned short* __restrict__ bfA, unsigned short* __restrict__ bfB,
    float* __restrict__ out) {
    const int lane = threadIdx.x & 63;
    const int w    = threadIdx.x >> 6;
    const int gw   = blockIdx.x * 4 + w;
    const int r4   = lane >> 4;
    const int g4   = lane & 15;
    const int row  = gw * 4 + r4;          // 0 .. BN_+BM_-1

    const float* src = (row < BN_) ? S1 + (size_t)row * C_
                                   : S2 + (size_t)(row - BN_) * C_;
    float4 v0 = ((const float4*)src)[g4 * 2];
    float4 v1 = ((const float4*)src)[g4 * 2 + 1];

    float s = v0.x*v0.x + v0.y*v0.y + v0.z*v0.z + v0.w*v0.w
            + v1.x*v1.x + v1.y*v1.y + v1.z*v1.z + v1.w*v1.w;
    s += __shfl_xor(s, 1, 64);
    s += __shfl_xor(s, 2, 64);
    s += __shfl_xor(s, 4, 64);
    s += __shfl_xor(s, 8, 64);

    ushort8 o;
    o[0] = f2bf(v0.x); o[1] = f2bf(v0.y); o[2] = f2bf(v0.z); o[3] = f2bf(v0.w);
    o[4] = f2bf(v1.x); o[5] = f2bf(v1.y); o[6] = f2bf(v1.z); o[7] = f2bf(v1.w);

    unsigned short* dst = (row < BN_) ? bfA + (size_t)row * C_
                                      : bfB + (size_t)(row - BN_) * C_;
    *(ushort8*)&dst[(g4 ^ (row & 15)) * 8] = o;

    if (g4 == 0) { norms[row] = s; minbuf[row] = 0x7F800000u; }
    if (blockIdx.x == 0 && threadIdx.x < B_) out[threadIdx.x] = 0.f;
}

// ---------------------------------------------------------------------------
// Main: grid (N/128, M/1024, B). 4 waves; wave tile = 64 rows x 32 cols.
// LDS: two 16 KB buffers. Pre-loop they hold the A tile (rows 0-63 / 64-127);
// in the loop they double-buffer 64-col B tiles.
// ---------------------------------------------------------------------------
__global__ __launch_bounds__(256, 4) void hausdorff_mfma(
    const unsigned short* __restrict__ Abf, const unsigned short* __restrict__ Bbf,
    const float* __restrict__ asq_g, const float* __restrict__ bsq_g,
    unsigned int* __restrict__ rowmin, unsigned int* __restrict__ colmin) {

    __shared__ unsigned short B_lds[2][64 * 128];   // 2 x 16 KB

    const int b     = blockIdx.z;
    const int row0  = blockIdx.x * 128;
    const int panel = blockIdx.y;                   // cols panel*1024 ..
    const int tid   = threadIdx.x;
    const int lane  = tid & 63;
    const int w     = tid >> 6;
    const int lm    = lane & 15;
    const int quad  = lane >> 4;
    const int wrow  = (w >> 1) * 64;                // wave's row half
    const int qc    = (w & 1) * 32;                 // wave's col half (of 64)

    const unsigned short* Aws = Abf + ((size_t)b * N_ + row0) * C_;
    const unsigned short* Bws = Bbf + ((size_t)b * M_ + panel * 1024) * C_;

    // ---- stage A through both buffers: rows 0-63 -> buf0, 64-127 -> buf1
    #pragma unroll
    for (int k = 0; k < 4; ++k) {
        const int off = w * 2048 + k * 512;         // ushorts
        gl2lds16(Aws + off + lane * 8,        &B_lds[0][off]);
        gl2lds16(Aws + 8192 + off + lane * 8, &B_lds[1][off]);
    }

    // row norms for this lane's 16 rows: wrow + 16i + 4*quad + reg
    float sa[16];
    #pragma unroll
    for (int i = 0; i < 4; ++i) {
        float4 t = *(const float4*)&asq_g[(size_t)b * N_ + row0 + wrow + 16 * i + 4 * quad];
        sa[4*i+0] = t.x; sa[4*i+1] = t.y; sa[4*i+2] = t.z; sa[4*i+3] = t.w;
    }

    float rv[16];
    #pragma unroll
    for (int v = 0; v < 16; ++v) rv[v] = 1e30f;

    __syncthreads();   // A staged

    // A fragments once; waves 0,1 from buf0 (rows 0-63), waves 2,3 from buf1
    bf16x8 af[4][4];
    {
        const unsigned short* Abuf = &B_lds[w >> 1][0];
        #pragma unroll
        for (int i = 0; i < 4; ++i)
            #pragma unroll
            for (int c = 0; c < 4; ++c)
                af[i][c] = *(const bf16x8*)
                    &Abuf[(16 * i + lm) * 128 + (((c * 4 + quad) ^ lm) * 8)];
    }

    __syncthreads();   // all af reads done -> buffers reusable

    // stage B tile 0 into buf0
    #pragma unroll
    for (int k = 0; k < 4; ++k) {
        const int off = w * 2048 + k * 512;
        gl2lds16(Bws + off + lane * 8, &B_lds[0][off]);
    }
    __syncthreads();   // B0 staged

    for (int it = 0; it < 16; ++it) {
        const int cur = it & 1;
        if (it < 15) {   // stage next tile into the other buffer
            const unsigned short* Bt = Bws + (size_t)(it + 1) * 64 * C_;
            #pragma unroll
            for (int k = 0; k < 4; ++k) {
                const int off = w * 2048 + k * 512;
                gl2lds16(Bt + off + lane * 8, &B_lds[cur ^ 1][off]);
            }
        }
        const int colbase = panel * 1024 + it * 64;
        const float sb0 = bsq_g[(size_t)b * M_ + colbase + qc + lm];
        const float sb1 = bsq_g[(size_t)b * M_ + colbase + qc + 16 + lm];

        bf16x8 bf[2][4];
        #pragma unroll
        for (int j = 0; j < 2; ++j)
            #pragma unroll
            for (int c = 0; c < 4; ++c)
                bf[j][c] = *(const bf16x8*)
                    &B_lds[cur][(qc + 16 * j + lm) * 128 + (((c * 4 + quad) ^ lm) * 8)];

        floatx4 acc[4][2] = {};
        #pragma unroll
        for (int c = 0; c < 4; ++c)
            #pragma unroll
            for (int i = 0; i < 4; ++i)
                #pragma unroll
                for (int j = 0; j < 2; ++j)
                    acc[i][j] = __builtin_amdgcn_mfma_f32_16x16x32_bf16(
                        af[i][c], bf[j][c], acc[i][j], 0, 0, 0);

        float cv0 = 1e30f, cv1 = 1e30f;
        #pragma unroll
        for (int i = 0; i < 4; ++i)
            #pragma unroll
            for (int reg = 0; reg < 4; ++reg) {
                const int v = 4 * i + reg;
                float d0 = fmaf(-2.0f, acc[i][0][reg], sa[v] + sb0);
                float d1 = fmaf(-2.0f, acc[i][1][reg], sa[v] + sb1);
                rv[v] = fminf(rv[v], fminf(d0, d1));   // -> v_min3
                cv0 = fminf(cv0, d0);
                cv1 = fminf(cv1, d1);
            }
        cv0 = fminf(cv0, __shfl_xor(cv0, 16, 64));
        cv0 = fminf(cv0, __shfl_xor(cv0, 32, 64));
        cv1 = fminf(cv1, __shfl_xor(cv1, 16, 64));
        cv1 = fminf(cv1, __shfl_xor(cv1, 32, 64));
        if (quad == 0) {
            atomicMin(&colmin[(size_t)b * M_ + colbase + qc + lm],
                      __float_as_uint(fmaxf(cv0, 0.f)));
            atomicMin(&colmin[(size_t)b * M_ + colbase + qc + 16 + lm],
                      __float_as_uint(fmaxf(cv1, 0.f)));
        }
        __syncthreads();   // buffer swap
    }

    // row mins: butterfly across the 16 lane-cols
    #pragma unroll
    for (int s = 1; s < 16; s <<= 1)
        #pragma unroll
        for (int v = 0; v < 16; ++v)
            rv[v] = fminf(rv[v], __shfl_xor(rv[v], s, 64));
    if (lm == 0) {
        #pragma unroll
        for (int v = 0; v < 16; ++v)
            atomicMin(&rowmin[(size_t)b * N_ + row0 + wrow + 16 * (v >> 2) +
                              4 * quad + (v & 3)],
                      __float_as_uint(fmaxf(rv[v], 0.f)));
    }
}

// ---------------------------------------------------------------------------
// Reduce: 64 blocks (8 per batch), partial sums -> atomicAdd(out[b]).
// ---------------------------------------------------------------------------
__global__ __launch_bounds__(256) void hausdorff_reduce(
    const unsigned int* __restrict__ rowmin,
    const unsigned int* __restrict__ colmin, float* __restrict__ out) {
    __shared__ float ws4[4];
    const int b    = blockIdx.x >> 3;
    const int part = blockIdx.x & 7;
    const int base = part * 512;
    float s = 0.f;
    for (int i = base + threadIdx.x; i < base + 512; i += 256)
        s += sqrtf(fmaxf(__uint_as_float(rowmin[(size_t)b * N_ + i]), 0.f)) * (1.f / N_)
           + sqrtf(fmaxf(__uint_as_float(colmin[(size_t)b * M_ + i]), 0.f)) * (1.f / M_);
    #pragma unroll
    for (int off = 32; off > 0; off >>= 1) s += __shfl_down(s, off, 64);
    if ((threadIdx.x & 63) == 0) ws4[threadIdx.x >> 6] = s;
    __syncthreads();
    if (threadIdx.x == 0)
        atomicAdd(&out[b], ws4[0] + ws4[1] + ws4[2] + ws4[3]);
}

extern "C" void kernel_launch(void* const* d_in, const int* in_sizes, int n_in,
                              void* d_out, int out_size, void* d_ws, size_t ws_size,
                              hipStream_t stream) {
    const float* s1 = (const float*)d_in[0];
    const float* s2 = (const float*)d_in[1];
    float* out = (float*)d_out;

    // ws: rowmin(BN u32) | colmin(BM u32) | norms(BN+BM f32) | bfA | bfB
    unsigned int* rowmin = (unsigned int*)d_ws;
    unsigned int* colmin = rowmin + BN_;
    float* norms         = (float*)(colmin + BM_);
    unsigned short* bfA  = (unsigned short*)(norms + BN_ + BM_);
    unsigned short* bfB  = bfA + (size_t)BN_ * C_;

    prep_kernel<<<(BN_ + BM_) / 16, 256, 0, stream>>>(
        s1, s2, rowmin, norms, bfA, bfB, out);

    dim3 grid(N_ / 128, M_ / 1024, B_);
    hausdorff_mfma<<<grid, 256, 0, stream>>>(
        bfA, bfB, norms, norms + BN_, rowmin, colmin);

    hausdorff_reduce<<<B_ * 8, 256, 0, stream>>>(rowmin, colmin, out);
}

// Round 8
// 122.972 us; speedup vs baseline: 2.6343x; 1.6113x over previous
//
#include <hip/hip_runtime.h>

// HausdorffLoss (average): B=8, N=M=4096, C=128, fp32 in/out.
// R8 = R7 structure with __launch_bounds__(256,2). The ",4" bound made the
// compiler split the 128-reg budget 64 arch + 64 acc -> spilled the hot
// arrays (R6/R7: VGPR_Count=64, 382 MB scratch FETCH). ",2" gives the
// R5-proven no-spill allocation; 32 KB LDS then allows 3 blocks/CU.
#define B_ 8
#define N_ 4096
#define M_ 4096
#define C_ 128
#define BN_ (B_ * N_)
#define BM_ (B_ * M_)

typedef __attribute__((ext_vector_type(8))) short bf16x8;    // MFMA A/B frag
typedef __attribute__((ext_vector_type(4))) float floatx4;   // MFMA C/D frag
typedef __attribute__((ext_vector_type(8))) unsigned short ushort8;

// fp32 -> bf16 round-to-nearest-even
__device__ __forceinline__ unsigned short f2bf(float x) {
    unsigned int u = __float_as_uint(x);
    u += 0x7FFFu + ((u >> 16) & 1u);
    return (unsigned short)(u >> 16);
}

// async global->LDS, 16 B per lane; LDS dest = wave-uniform base + lane*16
__device__ __forceinline__ void gl2lds16(const void* g, void* l) {
    __builtin_amdgcn_global_load_lds(
        (const __attribute__((address_space(1))) void*)g,
        (__attribute__((address_space(3))) void*)l, 16, 0, 0);
}

// ---------------------------------------------------------------------------
// Prep: bf16 convert (swizzled: ws[row][g ^ (row&15)] = src[row][g]),
// norms[row] = ||row||^2 (fp32), minbuf[row] = +inf, out zero-init.
// Wave handles 4 rows: lane = (row_in_4 : 2, k-group : 4).
// Grid = (BN_+BM_)/16 = 4096 blocks x 256 threads.
// ---------------------------------------------------------------------------
__global__ __launch_bounds__(256) void prep_kernel(
    const float* __restrict__ S1, const float* __restrict__ S2,
    unsigned int* __restrict__ minbuf, float* __restrict__ norms,
    unsigned short* __restrict__ bfA, unsigned short* __restrict__ bfB,
    float* __restrict__ out) {
    const int lane = threadIdx.x & 63;
    const int w    = threadIdx.x >> 6;
    const int gw   = blockIdx.x * 4 + w;
    const int r4   = lane >> 4;
    const int g4   = lane & 15;
    const int row  = gw * 4 + r4;          // 0 .. BN_+BM_-1

    const float* src = (row < BN_) ? S1 + (size_t)row * C_
                                   : S2 + (size_t)(row - BN_) * C_;
    float4 v0 = ((const float4*)src)[g4 * 2];
    float4 v1 = ((const float4*)src)[g4 * 2 + 1];

    float s = v0.x*v0.x + v0.y*v0.y + v0.z*v0.z + v0.w*v0.w
            + v1.x*v1.x + v1.y*v1.y + v1.z*v1.z + v1.w*v1.w;
    s += __shfl_xor(s, 1, 64);
    s += __shfl_xor(s, 2, 64);
    s += __shfl_xor(s, 4, 64);
    s += __shfl_xor(s, 8, 64);

    ushort8 o;
    o[0] = f2bf(v0.x); o[1] = f2bf(v0.y); o[2] = f2bf(v0.z); o[3] = f2bf(v0.w);
    o[4] = f2bf(v1.x); o[5] = f2bf(v1.y); o[6] = f2bf(v1.z); o[7] = f2bf(v1.w);

    unsigned short* dst = (row < BN_) ? bfA + (size_t)row * C_
                                      : bfB + (size_t)(row - BN_) * C_;
    *(ushort8*)&dst[(g4 ^ (row & 15)) * 8] = o;

    if (g4 == 0) { norms[row] = s; minbuf[row] = 0x7F800000u; }
    if (blockIdx.x == 0 && threadIdx.x < B_) out[threadIdx.x] = 0.f;
}

// ---------------------------------------------------------------------------
// Main: grid (N/128, M/1024, B). 4 waves; wave tile = 64 rows x 32 cols.
// LDS: two 16 KB buffers. Pre-loop they hold the A tile (rows 0-63 / 64-127);
// in the loop they double-buffer 64-col B tiles.
// ---------------------------------------------------------------------------
__global__ __launch_bounds__(256, 2) void hausdorff_mfma(
    const unsigned short* __restrict__ Abf, const unsigned short* __restrict__ Bbf,
    const float* __restrict__ asq_g, const float* __restrict__ bsq_g,
    unsigned int* __restrict__ rowmin, unsigned int* __restrict__ colmin) {

    __shared__ unsigned short B_lds[2][64 * 128];   // 2 x 16 KB

    const int b     = blockIdx.z;
    const int row0  = blockIdx.x * 128;
    const int panel = blockIdx.y;                   // cols panel*1024 ..
    const int tid   = threadIdx.x;
    const int lane  = tid & 63;
    const int w     = tid >> 6;
    const int lm    = lane & 15;
    const int quad  = lane >> 4;
    const int wrow  = (w >> 1) * 64;                // wave's row half
    const int qc    = (w & 1) * 32;                 // wave's col half (of 64)

    const unsigned short* Aws = Abf + ((size_t)b * N_ + row0) * C_;
    const unsigned short* Bws = Bbf + ((size_t)b * M_ + panel * 1024) * C_;

    // ---- stage A through both buffers: rows 0-63 -> buf0, 64-127 -> buf1
    #pragma unroll
    for (int k = 0; k < 4; ++k) {
        const int off = w * 2048 + k * 512;         // ushorts
        gl2lds16(Aws + off + lane * 8,        &B_lds[0][off]);
        gl2lds16(Aws + 8192 + off + lane * 8, &B_lds[1][off]);
    }

    // row norms for this lane's 16 rows: wrow + 16i + 4*quad + reg
    float sa[16];
    #pragma unroll
    for (int i = 0; i < 4; ++i) {
        float4 t = *(const float4*)&asq_g[(size_t)b * N_ + row0 + wrow + 16 * i + 4 * quad];
        sa[4*i+0] = t.x; sa[4*i+1] = t.y; sa[4*i+2] = t.z; sa[4*i+3] = t.w;
    }

    float rv[16];
    #pragma unroll
    for (int v = 0; v < 16; ++v) rv[v] = 1e30f;

    __syncthreads();   // A staged

    // A fragments once; waves 0,1 from buf0 (rows 0-63), waves 2,3 from buf1
    bf16x8 af[4][4];
    {
        const unsigned short* Abuf = &B_lds[w >> 1][0];
        #pragma unroll
        for (int i = 0; i < 4; ++i)
            #pragma unroll
            for (int c = 0; c < 4; ++c)
                af[i][c] = *(const bf16x8*)
                    &Abuf[(16 * i + lm) * 128 + (((c * 4 + quad) ^ lm) * 8)];
    }

    __syncthreads();   // all af reads done -> buffers reusable

    // stage B tile 0 into buf0
    #pragma unroll
    for (int k = 0; k < 4; ++k) {
        const int off = w * 2048 + k * 512;
        gl2lds16(Bws + off + lane * 8, &B_lds[0][off]);
    }
    __syncthreads();   // B0 staged

    for (int it = 0; it < 16; ++it) {
        const int cur = it & 1;
        if (it < 15) {   // stage next tile into the other buffer
            const unsigned short* Bt = Bws + (size_t)(it + 1) * 64 * C_;
            #pragma unroll
            for (int k = 0; k < 4; ++k) {
                const int off = w * 2048 + k * 512;
                gl2lds16(Bt + off + lane * 8, &B_lds[cur ^ 1][off]);
            }
        }
        const int colbase = panel * 1024 + it * 64;
        const float sb0 = bsq_g[(size_t)b * M_ + colbase + qc + lm];
        const float sb1 = bsq_g[(size_t)b * M_ + colbase + qc + 16 + lm];

        bf16x8 bf[2][4];
        #pragma unroll
        for (int j = 0; j < 2; ++j)
            #pragma unroll
            for (int c = 0; c < 4; ++c)
                bf[j][c] = *(const bf16x8*)
                    &B_lds[cur][(qc + 16 * j + lm) * 128 + (((c * 4 + quad) ^ lm) * 8)];

        floatx4 acc[4][2] = {};
        #pragma unroll
        for (int c = 0; c < 4; ++c)
            #pragma unroll
            for (int i = 0; i < 4; ++i)
                #pragma unroll
                for (int j = 0; j < 2; ++j)
                    acc[i][j] = __builtin_amdgcn_mfma_f32_16x16x32_bf16(
                        af[i][c], bf[j][c], acc[i][j], 0, 0, 0);

        float cv0 = 1e30f, cv1 = 1e30f;
        #pragma unroll
        for (int i = 0; i < 4; ++i)
            #pragma unroll
            for (int reg = 0; reg < 4; ++reg) {
                const int v = 4 * i + reg;
                float d0 = fmaf(-2.0f, acc[i][0][reg], sa[v] + sb0);
                float d1 = fmaf(-2.0f, acc[i][1][reg], sa[v] + sb1);
                rv[v] = fminf(rv[v], fminf(d0, d1));   // -> v_min3
                cv0 = fminf(cv0, d0);
                cv1 = fminf(cv1, d1);
            }
        cv0 = fminf(cv0, __shfl_xor(cv0, 16, 64));
        cv0 = fminf(cv0, __shfl_xor(cv0, 32, 64));
        cv1 = fminf(cv1, __shfl_xor(cv1, 16, 64));
        cv1 = fminf(cv1, __shfl_xor(cv1, 32, 64));
        if (quad == 0) {
            atomicMin(&colmin[(size_t)b * M_ + colbase + qc + lm],
                      __float_as_uint(fmaxf(cv0, 0.f)));
            atomicMin(&colmin[(size_t)b * M_ + colbase + qc + 16 + lm],
                      __float_as_uint(fmaxf(cv1, 0.f)));
        }
        __syncthreads();   // buffer swap
    }

    // row mins: butterfly across the 16 lane-cols
    #pragma unroll
    for (int s = 1; s < 16; s <<= 1)
        #pragma unroll
        for (int v = 0; v < 16; ++v)
            rv[v] = fminf(rv[v], __shfl_xor(rv[v], s, 64));
    if (lm == 0) {
        #pragma unroll
        for (int v = 0; v < 16; ++v)
            atomicMin(&rowmin[(size_t)b * N_ + row0 + wrow + 16 * (v >> 2) +
                              4 * quad + (v & 3)],
                      __float_as_uint(fmaxf(rv[v], 0.f)));
    }
}

// ---------------------------------------------------------------------------
// Reduce: 64 blocks (8 per batch), partial sums -> atomicAdd(out[b]).
// ---------------------------------------------------------------------------
__global__ __launch_bounds__(256) void hausdorff_reduce(
    const unsigned int* __restrict__ rowmin,
    const unsigned int* __restrict__ colmin, float* __restrict__ out) {
    __shared__ float ws4[4];
    const int b    = blockIdx.x >> 3;
    const int part = blockIdx.x & 7;
    const int base = part * 512;
    float s = 0.f;
    for (int i = base + threadIdx.x; i < base + 512; i += 256)
        s += sqrtf(fmaxf(__uint_as_float(rowmin[(size_t)b * N_ + i]), 0.f)) * (1.f / N_)
           + sqrtf(fmaxf(__uint_as_float(colmin[(size_t)b * M_ + i]), 0.f)) * (1.f / M_);
    #pragma unroll
    for (int off = 32; off > 0; off >>= 1) s += __shfl_down(s, off, 64);
    if ((threadIdx.x & 63) == 0) ws4[threadIdx.x >> 6] = s;
    __syncthreads();
    if (threadIdx.x == 0)
        atomicAdd(&out[b], ws4[0] + ws4[1] + ws4[2] + ws4[3]);
}

extern "C" void kernel_launch(void* const* d_in, const int* in_sizes, int n_in,
                              void* d_out, int out_size, void* d_ws, size_t ws_size,
                              hipStream_t stream) {
    const float* s1 = (const float*)d_in[0];
    const float* s2 = (const float*)d_in[1];
    float* out = (float*)d_out;

    // ws: rowmin(BN u32) | colmin(BM u32) | norms(BN+BM f32) | bfA | bfB
    unsigned int* rowmin = (unsigned int*)d_ws;
    unsigned int* colmin = rowmin + BN_;
    float* norms         = (float*)(colmin + BM_);
    unsigned short* bfA  = (unsigned short*)(norms + BN_ + BM_);
    unsigned short* bfB  = bfA + (size_t)BN_ * C_;

    prep_kernel<<<(BN_ + BM_) / 16, 256, 0, stream>>>(
        s1, s2, rowmin, norms, bfA, bfB, out);

    dim3 grid(N_ / 128, M_ / 1024, B_);
    hausdorff_mfma<<<grid, 256, 0, stream>>>(
        bfA, bfB, norms, norms + BN_, rowmin, colmin);

    hausdorff_reduce<<<B_ * 8, 256, 0, stream>>>(rowmin, colmin, out);
}